// Round 7
// baseline (867.375 us; speedup 1.0000x reference)
//
#include <hip/hip_runtime.h>

#define DIM 1024
#define SEQ 2048
#define BATCH 4
#define NH 16
#define HD 64
#define MLP 4096
#define ROWS (BATCH*SEQ)

typedef __bf16 bf16x8 __attribute__((ext_vector_type(8)));
typedef float f32x4 __attribute__((ext_vector_type(4)));
typedef __attribute__((address_space(3))) void as3void;
typedef const __attribute__((address_space(1))) void as1void;

__device__ __forceinline__ unsigned short f2bf(float f) {
  unsigned u = __builtin_bit_cast(unsigned, f);
  u = (u + 0x7FFFu + ((u >> 16) & 1u)) >> 16;
  return (unsigned short)u;
}

__device__ __forceinline__ void gload_lds16(const void* gp, const void* lp) {
  __builtin_amdgcn_global_load_lds(
      (as1void*)(unsigned long long)(size_t)gp,
      (as3void*)(unsigned int)(size_t)lp,
      16, 0, 0);
}

// ---------------- weight transpose fp32[K][N] -> bf16[N][K] ----------------
__global__ __launch_bounds__(256) void transpose_w_kernel(
    const float* __restrict__ in, unsigned short* __restrict__ out, int K, int N)
{
  __shared__ float tile[64][65];
  const int k0 = blockIdx.y * 64, n0 = blockIdx.x * 64;
  const int tc = threadIdx.x & 63, tr = threadIdx.x >> 6;
#pragma unroll
  for (int i = 0; i < 64; i += 4)
    tile[tr + i][tc] = in[(size_t)(k0 + tr + i) * N + n0 + tc];
  __syncthreads();
#pragma unroll
  for (int i = 0; i < 64; i += 4)
    out[(size_t)(n0 + tr + i) * K + k0 + tc] = f2bf(tile[tc][tr + i]);
}

// ---------------- layernorm fp32 -> bf16 ----------------
__global__ __launch_bounds__(256) void ln_kernel(
    const float* __restrict__ x, const float* __restrict__ w, const float* __restrict__ b,
    unsigned short* __restrict__ out)
{
  const int row = blockIdx.x;
  const int t = threadIdx.x;
  const int lane = t & 63, wave = t >> 6;
  const float* xr = x + (size_t)row * DIM;
  float4 v = *(const float4*)&xr[t * 4];
  float s = v.x + v.y + v.z + v.w;
  float s2 = v.x * v.x + v.y * v.y + v.z * v.z + v.w * v.w;
#pragma unroll
  for (int o = 1; o < 64; o <<= 1) {
    s += __shfl_xor(s, o);
    s2 += __shfl_xor(s2, o);
  }
  __shared__ float red[8];
  if (lane == 0) { red[wave] = s; red[4 + wave] = s2; }
  __syncthreads();
  s = red[0] + red[1] + red[2] + red[3];
  s2 = red[4] + red[5] + red[6] + red[7];
  const float mu = s * (1.f / DIM);
  const float var = s2 * (1.f / DIM) - mu * mu;
  const float rstd = rsqrtf(var + 1e-5f);
  float4 wv = *(const float4*)&w[t * 4];
  float4 bv = *(const float4*)&b[t * 4];
  ushort4 o;
  o.x = f2bf((v.x - mu) * rstd * wv.x + bv.x);
  o.y = f2bf((v.y - mu) * rstd * wv.y + bv.y);
  o.z = f2bf((v.z - mu) * rstd * wv.z + bv.z);
  o.w = f2bf((v.w - mu) * rstd * wv.w + bv.w);
  *(ushort4*)&out[(size_t)row * DIM + t * 4] = o;
}

// ---------------- GEMM: C[M][N] = A[M][K](bf16) x Bt[N][K](bf16) + bias ----------------
// m97 structure: 128x128 tile, BK=32, 4 waves, global_load_lds width 16.
// MODE 0: QKV scatter (Q scaled 0.125)  1: +res -> fp32  2: GELU -> bf16  3: +res -> fp32
template <int MODE>
__global__ __launch_bounds__(256) void gemm_bt(
    const unsigned short* __restrict__ A,
    const unsigned short* __restrict__ Bt,
    const float* __restrict__ bias,
    const float* resf, float* outf, unsigned short* outb,
    unsigned short* Qo, unsigned short* Ko, unsigned short* Vto,
    int M, int N, int K)
{
  __shared__ __align__(16) unsigned short sA[128 * 32];
  __shared__ __align__(16) unsigned short sB[128 * 32];
  const int tid = threadIdx.x;
  const int wave = tid >> 6, lane = tid & 63;

  // bijective XCD swizzle (all grids have nwg % 8 == 0)
  const int nbx = gridDim.x;
  const int nwg = nbx * gridDim.y;
  const int bid = blockIdx.y * nbx + blockIdx.x;
  const int cpx = nwg >> 3;
  const int swz = (bid & 7) * cpx + (bid >> 3);
  const int n0 = (swz % nbx) * 128;
  const int m0 = (swz / nbx) * 128;

  const int srow = wave * 16 + (lane >> 2);
  const int scol = (lane & 3) * 8;
  const unsigned short* gA = A + (size_t)(m0 + srow) * K + scol;
  const unsigned short* gB = Bt + (size_t)(n0 + srow) * K + scol;
  unsigned short* lA0 = sA + wave * 512;
  unsigned short* lA1 = sA + 2048 + wave * 512;
  unsigned short* lB0 = sB + wave * 512;
  unsigned short* lB1 = sB + 2048 + wave * 512;
  const size_t rstep = (size_t)64 * K;

  const int wr = wave >> 1, wc = wave & 1;
  const int fl = lane & 15, fh = lane >> 4;
  f32x4 acc[4][4] = {};

  for (int k0 = 0; k0 < K; k0 += 32) {
    gload_lds16(gA + k0, lA0);
    gload_lds16(gA + rstep + k0, lA1);
    gload_lds16(gB + k0, lB0);
    gload_lds16(gB + rstep + k0, lB1);
    __syncthreads();
    bf16x8 af[4], bfr[4];
#pragma unroll
    for (int f = 0; f < 4; ++f)
      af[f] = *(const bf16x8*)&sA[(wr * 64 + f * 16 + fl) * 32 + fh * 8];
#pragma unroll
    for (int f = 0; f < 4; ++f)
      bfr[f] = *(const bf16x8*)&sB[(wc * 64 + f * 16 + fl) * 32 + fh * 8];
#pragma unroll
    for (int i = 0; i < 4; ++i)
#pragma unroll
      for (int j = 0; j < 4; ++j)
        acc[i][j] = __builtin_amdgcn_mfma_f32_16x16x32_bf16(af[i], bfr[j], acc[i][j], 0, 0, 0);
    __syncthreads();
  }

#pragma unroll
  for (int i = 0; i < 4; ++i) {
    const int rowb = m0 + wr * 64 + i * 16 + fh * 4;
#pragma unroll
    for (int j = 0; j < 4; ++j) {
      const int col = n0 + wc * 64 + j * 16 + fl;
      const float bv = bias[col];
#pragma unroll
      for (int r = 0; r < 4; ++r) {
        const int row = rowb + r;
        float v = acc[i][j][r] + bv;
        if constexpr (MODE == 0) {
          const int which = col >> 10;
          const int h = (col >> 6) & 15;
          const int d = col & 63;
          const int b = row >> 11, s = row & 2047;
          const size_t bh = (size_t)(b * 16 + h);
          if (which == 0)      Qo[(bh * SEQ + s) * HD + d] = f2bf(v * 0.125f);
          else if (which == 1) Ko[(bh * SEQ + s) * HD + d] = f2bf(v);
          else                 Vto[(bh * HD + d) * SEQ + s] = f2bf(v);
        } else if constexpr (MODE == 2) {
          const float g = 0.5f * v * (1.0f + erff(v * 0.70710678118f));
          outb[(size_t)row * N + col] = f2bf(g);
        } else {
          outf[(size_t)row * N + col] = resf[(size_t)row * N + col] + v;
        }
      }
    }
  }
}

// ---------------- causal flash attention (v3: swapped operands) ----------------
// grid (32 qtiles heavy-first, 64 bh); 4 waves; each wave owns 16 q-rows.
// S^T = mfma(K,Q): each lane owns ONE q-row -> softmax reduce = in-reg + 2 shfl.
// K staged in LDS (dbuf, swizzled-source); V read direct from global (L2-fit).
__global__ __launch_bounds__(256, 5) void attn_kernel(
    const unsigned short* __restrict__ Q,
    const unsigned short* __restrict__ Kt,
    const unsigned short* __restrict__ Vt,
    unsigned short* __restrict__ Ao)
{
  __shared__ __align__(16) char sK[2][8192];
  __shared__ __align__(16) char sP[4][2048];

  const int qt = 31 - blockIdx.x;            // heavy blocks dispatch first
  const int bh = blockIdx.y;
  const int wave = threadIdx.x >> 6, lane = threadIdx.x & 63;
  const int fl = lane & 15, fh = lane >> 4;
  const int q0 = qt * 64;
  const int qw = q0 + wave * 16;
  const char* Kb = (const char*)(Kt + (size_t)bh * SEQ * HD);
  const unsigned short* Vb = Vt + (size_t)bh * HD * SEQ;
  const unsigned short* Qb = Q + (size_t)bh * SEQ * HD;
  char* pbase = sP[wave];
  const int pswz = (fl & 7) << 4;

  // K staging geometry: 8KB tile = 8 chunks of 1KB; wave stages chunks {wave, wave+4}
  const int sg_row_in = lane >> 3;            // row & 7 within chunk
  const int sg_colb = ((lane & 7) * 16) ^ (sg_row_in << 4); // pre-swizzled src col

  // Q fragment (B-operand of swapped QK): lane fl holds Q[qw+fl][kk*32+fh*8..+8]
  bf16x8 bq[2];
#pragma unroll
  for (int kk = 0; kk < 2; ++kk)
    bq[kk] = *(const bf16x8*)&Qb[(size_t)(qw + fl) * HD + kk * 32 + fh * 8];

  f32x4 accO[4] = {};                        // O[q=qw+fl][d = dc*16 + fh*4 + r]
  float mr = -1e30f, lr = 0.f;               // one q-row per lane

  const int nkt = qt + 1;                    // uniform across waves (no divergence)

  // prologue: stage K tile 0 into buf 0
#pragma unroll
  for (int i = 0; i < 2; ++i) {
    const int chunk = i * 4 + wave;
    const int row = chunk * 8 + sg_row_in;
    gload_lds16(Kb + (size_t)row * 128 + sg_colb, sK[0] + chunk * 1024);
  }
  __syncthreads();

  for (int t = 0; t < nkt; ++t) {
    const int kbase = t * 64;
    const int cur = t & 1;
    if (t + 1 < nkt) { // prefetch next K tile
#pragma unroll
      for (int i = 0; i < 2; ++i) {
        const int chunk = i * 4 + wave;
        const int row = chunk * 8 + sg_row_in;
        gload_lds16(Kb + (size_t)(kbase + 64 + row) * 128 + sg_colb,
                    sK[cur ^ 1] + chunk * 1024);
      }
    }

    // ---- S^T = K * Q^T : accT[fc][r] = S[k=kbase+fc*16+fh*4+r][q=qw+fl] ----
    f32x4 accT[4] = {};
    __builtin_amdgcn_s_setprio(1);
#pragma unroll
    for (int kk = 0; kk < 2; ++kk) {
      const int cb = (kk * 64 + fh * 16) ^ pswz;
#pragma unroll
      for (int fc = 0; fc < 4; ++fc) {
        const bf16x8 ak = *(const bf16x8*)(sK[cur] + (fc * 16 + fl) * 128 + cb);
        accT[fc] = __builtin_amdgcn_mfma_f32_16x16x32_bf16(ak, bq[kk], accT[fc], 0, 0, 0);
      }
    }
    __builtin_amdgcn_s_setprio(0);

    // ---- V fragments for this tile (direct global, L2-resident) ----
    // issued now so softmax hides the load latency (T14 pattern)
    bf16x8 vf[2][4];
#pragma unroll
    for (int kk = 0; kk < 2; ++kk)
#pragma unroll
      for (int dc = 0; dc < 4; ++dc)
        vf[kk][dc] = *(const bf16x8*)&Vb[(size_t)(dc * 16 + fl) * SEQ + kbase + kk * 32 + fh * 8];

    if (t == nkt - 1) { // causal mask (diagonal tile only)
      const int rowq = qw + fl;
#pragma unroll
      for (int fc = 0; fc < 4; ++fc)
#pragma unroll
        for (int r = 0; r < 4; ++r) {
          const int colk = kbase + fc * 16 + fh * 4 + r;
          if (colk > rowq) accT[fc][r] = -1e30f;
        }
    }

    // ---- online softmax: each lane owns one q-row (16 in-reg + 2 shfl) ----
    float mx = fmaxf(fmaxf(fmaxf(accT[0][0], accT[0][1]), fmaxf(accT[0][2], accT[0][3])),
                     fmaxf(fmaxf(accT[1][0], accT[1][1]), fmaxf(accT[1][2], accT[1][3])));
    mx = fmaxf(mx, fmaxf(fmaxf(fmaxf(accT[2][0], accT[2][1]), fmaxf(accT[2][2], accT[2][3])),
                         fmaxf(fmaxf(accT[3][0], accT[3][1]), fmaxf(accT[3][2], accT[3][3]))));
    mx = fmaxf(mx, __shfl_xor(mx, 16));
    mx = fmaxf(mx, __shfl_xor(mx, 32));
    const float mnew = fmaxf(mr, mx);
    const float alpha = __expf(mr - mnew);
    mr = mnew;
    float rs = 0.f;
#pragma unroll
    for (int fc = 0; fc < 4; ++fc)
#pragma unroll
      for (int r = 0; r < 4; ++r) {
        const float p = __expf(accT[fc][r] - mnew);
        accT[fc][r] = p;
        rs += p;
      }
    rs += __shfl_xor(rs, 16);
    rs += __shfl_xor(rs, 32);
    lr = lr * alpha + rs;
#pragma unroll
    for (int dc = 0; dc < 4; ++dc)
      accO[dc] *= alpha;

    // ---- P -> LDS as [q=fl][k] row-major 128B rows, XOR-swizzled ----
#pragma unroll
    for (int fc = 0; fc < 4; ++fc)
#pragma unroll
      for (int r = 0; r < 4; ++r) {
        const int k = fc * 16 + fh * 4 + r;
        *(unsigned short*)(pbase + fl * 128 + ((k * 2) ^ pswz)) = f2bf(accT[fc][r]);
      }

    // ---- O^T += V^T * P^T ----
    __builtin_amdgcn_s_setprio(1);
#pragma unroll
    for (int kk = 0; kk < 2; ++kk) {
      const bf16x8 pb = *(const bf16x8*)(pbase + fl * 128 + ((kk * 64 + fh * 16) ^ pswz));
#pragma unroll
      for (int dc = 0; dc < 4; ++dc)
        accO[dc] = __builtin_amdgcn_mfma_f32_16x16x32_bf16(vf[kk][dc], pb, accO[dc], 0, 0, 0);
    }
    __builtin_amdgcn_s_setprio(0);

    __syncthreads(); // protects sK dbuf swap (drains K prefetch)
  }

  // epilogue: lane owns q-row qw+fl; d = dc*16 + fh*4 + r (r contiguous)
  const int b = bh >> 4, h = bh & 15;
  const float inv = 1.0f / lr;
  unsigned short* orow = Ao + ((size_t)b * SEQ + qw + fl) * DIM + h * HD;
#pragma unroll
  for (int dc = 0; dc < 4; ++dc) {
    ushort4 o;
    o.x = f2bf(accO[dc][0] * inv);
    o.y = f2bf(accO[dc][1] * inv);
    o.z = f2bf(accO[dc][2] * inv);
    o.w = f2bf(accO[dc][3] * inv);
    *(ushort4*)&orow[dc * 16 + fh * 4] = o;
  }
}

// ---------------- launcher ----------------
extern "C" void kernel_launch(void* const* d_in, const int* in_sizes, int n_in,
                              void* d_out, int out_size, void* d_ws, size_t ws_size,
                              hipStream_t stream)
{
  const float* x      = (const float*)d_in[0];
  const float* ln1_w  = (const float*)d_in[1];
  const float* ln1_b  = (const float*)d_in[2];
  const float* qkv_w  = (const float*)d_in[3];
  const float* qkv_b  = (const float*)d_in[4];
  const float* proj_w = (const float*)d_in[5];
  const float* proj_b = (const float*)d_in[6];
  const float* ln2_w  = (const float*)d_in[7];
  const float* ln2_b  = (const float*)d_in[8];
  const float* fc1_w  = (const float*)d_in[9];
  const float* fc1_b  = (const float*)d_in[10];
  const float* fc2_w  = (const float*)d_in[11];
  const float* fc2_b  = (const float*)d_in[12];
  float* out = (float*)d_out;
  unsigned short* ws = (unsigned short*)d_ws;

  // ws layout (bf16 element offsets); total = 125,829,120 bytes
  unsigned short* wqkv = ws;                 // [3072][1024]
  unsigned short* wproj = ws + 3145728;      // [1024][1024]
  unsigned short* wfc1 = ws + 4194304;       // [4096][1024]
  unsigned short* wfc2 = ws + 8388608;       // [1024][4096]
  unsigned short* xn1  = ws + 12582912;      // [8192][1024]
  unsigned short* Qb   = ws + 20971520;      // [B,H,S,D]
  unsigned short* Kb   = ws + 29360128;      // [B,H,S,D]
  unsigned short* Vtb  = ws + 37748736;      // [B,H,D,S]
  unsigned short* aout = xn1;                // reuse (xn1 dead after QKV gemm)
  unsigned short* hn   = Qb;                 // reuse (Q dead after attention)
  unsigned short* hbuf = Kb;                 // [8192][4096] overlaps K/Vt (dead)

  transpose_w_kernel<<<dim3(48, 16), 256, 0, stream>>>(qkv_w, wqkv, 1024, 3072);
  transpose_w_kernel<<<dim3(16, 16), 256, 0, stream>>>(proj_w, wproj, 1024, 1024);
  transpose_w_kernel<<<dim3(64, 16), 256, 0, stream>>>(fc1_w, wfc1, 1024, 4096);
  transpose_w_kernel<<<dim3(16, 64), 256, 0, stream>>>(fc2_w, wfc2, 4096, 1024);

  ln_kernel<<<ROWS, 256, 0, stream>>>(x, ln1_w, ln1_b, xn1);

  gemm_bt<0><<<dim3(24, 64), 256, 0, stream>>>(xn1, wqkv, qkv_b,
      nullptr, nullptr, nullptr, Qb, Kb, Vtb, ROWS, 3072, 1024);

  attn_kernel<<<dim3(32, 64), 256, 0, stream>>>(Qb, Kb, Vtb, aout);

  gemm_bt<1><<<dim3(8, 64), 256, 0, stream>>>(aout, wproj, proj_b,
      x, out, nullptr, nullptr, nullptr, nullptr, ROWS, 1024, 1024);

  ln_kernel<<<ROWS, 256, 0, stream>>>(out, ln2_w, ln2_b, hn);

  gemm_bt<2><<<dim3(32, 64), 256, 0, stream>>>(hn, wfc1, fc1_b,
      nullptr, nullptr, hbuf, nullptr, nullptr, nullptr, ROWS, 4096, 1024);

  gemm_bt<3><<<dim3(8, 64), 256, 0, stream>>>(hbuf, wfc2, fc2_b,
      out, out, nullptr, nullptr, nullptr, nullptr, ROWS, 1024, 4096);
}

// Round 9
// 598.327 us; speedup vs baseline: 1.4497x; 1.4497x over previous
//
#include <hip/hip_runtime.h>

#define DIM 1024
#define SEQ 2048
#define BATCH 4
#define NH 16
#define HD 64
#define MLP 4096
#define ROWS (BATCH*SEQ)

typedef __bf16 bf16x8 __attribute__((ext_vector_type(8)));
typedef float f32x4 __attribute__((ext_vector_type(4)));
typedef __attribute__((address_space(3))) void as3void;
typedef const __attribute__((address_space(1))) void as1void;

__device__ __forceinline__ unsigned short f2bf(float f) {
  unsigned u = __builtin_bit_cast(unsigned, f);
  u = (u + 0x7FFFu + ((u >> 16) & 1u)) >> 16;
  return (unsigned short)u;
}

__device__ __forceinline__ void gload_lds16(const void* gp, const void* lp) {
  __builtin_amdgcn_global_load_lds(
      (as1void*)(unsigned long long)(size_t)gp,
      (as3void*)(unsigned int)(size_t)lp,
      16, 0, 0);
}

// ---------------- weight transpose fp32[K][N] -> bf16[N][K] ----------------
__global__ __launch_bounds__(256) void transpose_w_kernel(
    const float* __restrict__ in, unsigned short* __restrict__ out, int K, int N)
{
  __shared__ float tile[64][65];
  const int k0 = blockIdx.y * 64, n0 = blockIdx.x * 64;
  const int tc = threadIdx.x & 63, tr = threadIdx.x >> 6;
#pragma unroll
  for (int i = 0; i < 64; i += 4)
    tile[tr + i][tc] = in[(size_t)(k0 + tr + i) * N + n0 + tc];
  __syncthreads();
#pragma unroll
  for (int i = 0; i < 64; i += 4)
    out[(size_t)(n0 + tr + i) * K + k0 + tc] = f2bf(tile[tc][tr + i]);
}

// ---------------- layernorm fp32 -> bf16 ----------------
__global__ __launch_bounds__(256) void ln_kernel(
    const float* __restrict__ x, const float* __restrict__ w, const float* __restrict__ b,
    unsigned short* __restrict__ out)
{
  const int row = blockIdx.x;
  const int t = threadIdx.x;
  const int lane = t & 63, wave = t >> 6;
  const float* xr = x + (size_t)row * DIM;
  float4 v = *(const float4*)&xr[t * 4];
  float s = v.x + v.y + v.z + v.w;
  float s2 = v.x * v.x + v.y * v.y + v.z * v.z + v.w * v.w;
#pragma unroll
  for (int o = 1; o < 64; o <<= 1) {
    s += __shfl_xor(s, o);
    s2 += __shfl_xor(s2, o);
  }
  __shared__ float red[8];
  if (lane == 0) { red[wave] = s; red[4 + wave] = s2; }
  __syncthreads();
  s = red[0] + red[1] + red[2] + red[3];
  s2 = red[4] + red[5] + red[6] + red[7];
  const float mu = s * (1.f / DIM);
  const float var = s2 * (1.f / DIM) - mu * mu;
  const float rstd = rsqrtf(var + 1e-5f);
  float4 wv = *(const float4*)&w[t * 4];
  float4 bv = *(const float4*)&b[t * 4];
  ushort4 o;
  o.x = f2bf((v.x - mu) * rstd * wv.x + bv.x);
  o.y = f2bf((v.y - mu) * rstd * wv.y + bv.y);
  o.z = f2bf((v.z - mu) * rstd * wv.z + bv.z);
  o.w = f2bf((v.w - mu) * rstd * wv.w + bv.w);
  *(ushort4*)&out[(size_t)row * DIM + t * 4] = o;
}

// ---------------- GEMM: C[M][N] = A[M][K](bf16) x Bt[N][K](bf16) + bias ----------------
// m97 structure: 128x128 tile, BK=32, 4 waves, global_load_lds width 16.
// MODE 0: QKV scatter (Q scaled 0.125)  1: +res -> fp32  2: GELU -> bf16  3: +res -> fp32
template <int MODE>
__global__ __launch_bounds__(256) void gemm_bt(
    const unsigned short* __restrict__ A,
    const unsigned short* __restrict__ Bt,
    const float* __restrict__ bias,
    const float* resf, float* outf, unsigned short* outb,
    unsigned short* Qo, unsigned short* Ko, unsigned short* Vto,
    int M, int N, int K)
{
  __shared__ __align__(16) unsigned short sA[128 * 32];
  __shared__ __align__(16) unsigned short sB[128 * 32];
  const int tid = threadIdx.x;
  const int wave = tid >> 6, lane = tid & 63;

  // bijective XCD swizzle (all grids have nwg % 8 == 0)
  const int nbx = gridDim.x;
  const int nwg = nbx * gridDim.y;
  const int bid = blockIdx.y * nbx + blockIdx.x;
  const int cpx = nwg >> 3;
  const int swz = (bid & 7) * cpx + (bid >> 3);
  const int n0 = (swz % nbx) * 128;
  const int m0 = (swz / nbx) * 128;

  const int srow = wave * 16 + (lane >> 2);
  const int scol = (lane & 3) * 8;
  const unsigned short* gA = A + (size_t)(m0 + srow) * K + scol;
  const unsigned short* gB = Bt + (size_t)(n0 + srow) * K + scol;
  unsigned short* lA0 = sA + wave * 512;
  unsigned short* lA1 = sA + 2048 + wave * 512;
  unsigned short* lB0 = sB + wave * 512;
  unsigned short* lB1 = sB + 2048 + wave * 512;
  const size_t rstep = (size_t)64 * K;

  const int wr = wave >> 1, wc = wave & 1;
  const int fl = lane & 15, fh = lane >> 4;
  f32x4 acc[4][4] = {};

  for (int k0 = 0; k0 < K; k0 += 32) {
    gload_lds16(gA + k0, lA0);
    gload_lds16(gA + rstep + k0, lA1);
    gload_lds16(gB + k0, lB0);
    gload_lds16(gB + rstep + k0, lB1);
    __syncthreads();
    bf16x8 af[4], bfr[4];
#pragma unroll
    for (int f = 0; f < 4; ++f)
      af[f] = *(const bf16x8*)&sA[(wr * 64 + f * 16 + fl) * 32 + fh * 8];
#pragma unroll
    for (int f = 0; f < 4; ++f)
      bfr[f] = *(const bf16x8*)&sB[(wc * 64 + f * 16 + fl) * 32 + fh * 8];
#pragma unroll
    for (int i = 0; i < 4; ++i)
#pragma unroll
      for (int j = 0; j < 4; ++j)
        acc[i][j] = __builtin_amdgcn_mfma_f32_16x16x32_bf16(af[i], bfr[j], acc[i][j], 0, 0, 0);
    __syncthreads();
  }

#pragma unroll
  for (int i = 0; i < 4; ++i) {
    const int rowb = m0 + wr * 64 + i * 16 + fh * 4;
#pragma unroll
    for (int j = 0; j < 4; ++j) {
      const int col = n0 + wc * 64 + j * 16 + fl;
      const float bv = bias[col];
#pragma unroll
      for (int r = 0; r < 4; ++r) {
        const int row = rowb + r;
        float v = acc[i][j][r] + bv;
        if constexpr (MODE == 0) {
          const int which = col >> 10;
          const int h = (col >> 6) & 15;
          const int d = col & 63;
          const int b = row >> 11, s = row & 2047;
          const size_t bh = (size_t)(b * 16 + h);
          if (which == 0)      Qo[(bh * SEQ + s) * HD + d] = f2bf(v * 0.125f);
          else if (which == 1) Ko[(bh * SEQ + s) * HD + d] = f2bf(v);
          else                 Vto[(bh * HD + d) * SEQ + s] = f2bf(v);
        } else if constexpr (MODE == 2) {
          const float g = 0.5f * v * (1.0f + erff(v * 0.70710678118f));
          outb[(size_t)row * N + col] = f2bf(g);
        } else {
          outf[(size_t)row * N + col] = resf[(size_t)row * N + col] + v;
        }
      }
    }
  }
}

// ---------------- causal flash attention (v4: swapped ops + balanced pairing) ----------------
// grid (16, 64 bh); block bx processes qt=bx THEN qt=31-bx  => exactly 33 K-tiles
// per block (perfect balance; 1024 blocks x 40KB = all-resident at 4 blocks/CU).
// S^T = mfma(K,Q): lane owns one q-row -> softmax = in-reg + 2 shfl.
// K AND V staged in LDS (dbuf, pre-swizzled global source, 0-conflict pattern).
// P bounced via per-wave LDS as 4x 8B packed stores (conflict-light).
__global__ __launch_bounds__(256, 4) void attn_kernel(
    const unsigned short* __restrict__ Q,
    const unsigned short* __restrict__ Kt,
    const unsigned short* __restrict__ Vt,
    unsigned short* __restrict__ Ao)
{
  __shared__ __align__(16) char sK[2][8192];
  __shared__ __align__(16) char sV[2][8192];
  __shared__ __align__(16) char sP[4][2048];

  const int bh = blockIdx.y;
  const int wave = threadIdx.x >> 6, lane = threadIdx.x & 63;
  const int fl = lane & 15, fh = lane >> 4;
  const char* Kb = (const char*)(Kt + (size_t)bh * SEQ * HD);
  const char* Vb = (const char*)(Vt + (size_t)bh * HD * SEQ);
  const unsigned short* Qb = Q + (size_t)bh * SEQ * HD;
  char* pbase = sP[wave];
  const int pswz = (fl & 7) << 4;
  const int b = bh >> 4, h = bh & 15;

  // staging geometry: 8KB tile = 8 chunks of 1KB; wave stages chunks {wave, wave+4}
  const int sg_row_in = lane >> 3;                          // row & 7 within chunk
  const int sg_colb = ((lane & 7) * 16) ^ (sg_row_in << 4); // pre-swizzled src col

  for (int phase = 0; phase < 2; ++phase) {
    const int qt = (phase == 0) ? (int)blockIdx.x : 31 - (int)blockIdx.x;
    const int qw = qt * 64 + wave * 16;
    const int nkt = qt + 1;                 // uniform across waves

    // Q fragment (B-operand of swapped QK): lane fl holds Q[qw+fl][kk*32+fh*8..+8]
    bf16x8 bq[2];
#pragma unroll
    for (int kk = 0; kk < 2; ++kk)
      bq[kk] = *(const bf16x8*)&Qb[(size_t)(qw + fl) * HD + kk * 32 + fh * 8];

    f32x4 accO[4] = {};                     // O[q=qw+fl][d = dc*16 + fh*4 + r]
    float mr = -1e30f, lr = 0.f;

    // prologue: stage K/V tile 0 into buf 0
#pragma unroll
    for (int i = 0; i < 2; ++i) {
      const int chunk = i * 4 + wave;
      const int row = chunk * 8 + sg_row_in;
      gload_lds16(Kb + (size_t)row * 128 + sg_colb, sK[0] + chunk * 1024);
      gload_lds16(Vb + (size_t)row * (SEQ * 2) + sg_colb, sV[0] + chunk * 1024);
    }
    __syncthreads();

    for (int t = 0; t < nkt; ++t) {
      const int kbase = t * 64;
      const int cur = t & 1;
      if (t + 1 < nkt) { // prefetch next K/V tile into other buffer
        const int kb2 = kbase + 64;
#pragma unroll
        for (int i = 0; i < 2; ++i) {
          const int chunk = i * 4 + wave;
          const int row = chunk * 8 + sg_row_in;
          gload_lds16(Kb + (size_t)(kb2 + row) * 128 + sg_colb, sK[cur ^ 1] + chunk * 1024);
          gload_lds16(Vb + (size_t)row * (SEQ * 2) + kb2 * 2 + sg_colb, sV[cur ^ 1] + chunk * 1024);
        }
      }

      // ---- S^T = K * Q^T : accT[fc][r] = S[q=qw+fl][k=kbase+fc*16+fh*4+r] ----
      f32x4 accT[4] = {};
      __builtin_amdgcn_s_setprio(1);
#pragma unroll
      for (int kk = 0; kk < 2; ++kk) {
        const int cb = (kk * 64 + fh * 16) ^ pswz;
#pragma unroll
        for (int fc = 0; fc < 4; ++fc) {
          const bf16x8 ak = *(const bf16x8*)(sK[cur] + (fc * 16 + fl) * 128 + cb);
          accT[fc] = __builtin_amdgcn_mfma_f32_16x16x32_bf16(ak, bq[kk], accT[fc], 0, 0, 0);
        }
      }
      __builtin_amdgcn_s_setprio(0);

      if (t == nkt - 1) { // causal mask (diagonal tile only)
        const int rowq = qw + fl;
#pragma unroll
        for (int fc = 0; fc < 4; ++fc)
#pragma unroll
          for (int r = 0; r < 4; ++r) {
            const int colk = kbase + fc * 16 + fh * 4 + r;
            if (colk > rowq) accT[fc][r] = -1e30f;
          }
      }

      // ---- online softmax: lane owns one q-row (15 in-reg max + 2 shfl) ----
      float mx = fmaxf(fmaxf(fmaxf(accT[0][0], accT[0][1]), fmaxf(accT[0][2], accT[0][3])),
                       fmaxf(fmaxf(accT[1][0], accT[1][1]), fmaxf(accT[1][2], accT[1][3])));
      mx = fmaxf(mx, fmaxf(fmaxf(fmaxf(accT[2][0], accT[2][1]), fmaxf(accT[2][2], accT[2][3])),
                           fmaxf(fmaxf(accT[3][0], accT[3][1]), fmaxf(accT[3][2], accT[3][3]))));
      mx = fmaxf(mx, __shfl_xor(mx, 16));
      mx = fmaxf(mx, __shfl_xor(mx, 32));
      const float mnew = fmaxf(mr, mx);
      const float alpha = __expf(mr - mnew);
      mr = mnew;
      float rs = 0.f;
#pragma unroll
      for (int fc = 0; fc < 4; ++fc)
#pragma unroll
        for (int r = 0; r < 4; ++r) {
          const float p = __expf(accT[fc][r] - mnew);
          accT[fc][r] = p;
          rs += p;
        }
      rs += __shfl_xor(rs, 16);
      rs += __shfl_xor(rs, 32);
      lr = lr * alpha + rs;
#pragma unroll
      for (int dc = 0; dc < 4; ++dc)
        accO[dc] *= alpha;

      // ---- P -> LDS: pack r-quad to 8B, one store per fc (same byte image) ----
#pragma unroll
      for (int fc = 0; fc < 4; ++fc) {
        uint2 pk;
        pk.x = (unsigned)f2bf(accT[fc][0]) | ((unsigned)f2bf(accT[fc][1]) << 16);
        pk.y = (unsigned)f2bf(accT[fc][2]) | ((unsigned)f2bf(accT[fc][3]) << 16);
        *(uint2*)(pbase + fl * 128 + ((fc * 32 + fh * 8) ^ pswz)) = pk;
      }

      // ---- O^T += V^T * P^T (V from LDS, 0-conflict swizzled reads) ----
      __builtin_amdgcn_s_setprio(1);
#pragma unroll
      for (int kk = 0; kk < 2; ++kk) {
        const int cb = (kk * 64 + fh * 16) ^ pswz;
        const bf16x8 pb = *(const bf16x8*)(pbase + fl * 128 + cb);
#pragma unroll
        for (int dc = 0; dc < 4; ++dc) {
          const bf16x8 av = *(const bf16x8*)(sV[cur] + (dc * 16 + fl) * 128 + cb);
          accO[dc] = __builtin_amdgcn_mfma_f32_16x16x32_bf16(av, pb, accO[dc], 0, 0, 0);
        }
      }
      __builtin_amdgcn_s_setprio(0);

      __syncthreads(); // protects dbuf swap (drains prefetch)
    }

    // epilogue: lane owns q-row qw+fl; d = dc*16 + fh*4 + r
    const float inv = 1.0f / lr;
    unsigned short* orow = Ao + ((size_t)b * SEQ + qw + fl) * DIM + h * HD;
#pragma unroll
    for (int dc = 0; dc < 4; ++dc) {
      ushort4 o;
      o.x = f2bf(accO[dc][0] * inv);
      o.y = f2bf(accO[dc][1] * inv);
      o.z = f2bf(accO[dc][2] * inv);
      o.w = f2bf(accO[dc][3] * inv);
      *(ushort4*)&orow[dc * 16 + fh * 4] = o;
    }
  }
}

// ---------------- launcher ----------------
extern "C" void kernel_launch(void* const* d_in, const int* in_sizes, int n_in,
                              void* d_out, int out_size, void* d_ws, size_t ws_size,
                              hipStream_t stream)
{
  const float* x      = (const float*)d_in[0];
  const float* ln1_w  = (const float*)d_in[1];
  const float* ln1_b  = (const float*)d_in[2];
  const float* qkv_w  = (const float*)d_in[3];
  const float* qkv_b  = (const float*)d_in[4];
  const float* proj_w = (const float*)d_in[5];
  const float* proj_b = (const float*)d_in[6];
  const float* ln2_w  = (const float*)d_in[7];
  const float* ln2_b  = (const float*)d_in[8];
  const float* fc1_w  = (const float*)d_in[9];
  const float* fc1_b  = (const float*)d_in[10];
  const float* fc2_w  = (const float*)d_in[11];
  const float* fc2_b  = (const float*)d_in[12];
  float* out = (float*)d_out;
  unsigned short* ws = (unsigned short*)d_ws;

  // ws layout (bf16 element offsets); total = 125,829,120 bytes
  unsigned short* wqkv = ws;                 // [3072][1024]
  unsigned short* wproj = ws + 3145728;      // [1024][1024]
  unsigned short* wfc1 = ws + 4194304;       // [4096][1024]
  unsigned short* wfc2 = ws + 8388608;       // [1024][4096]
  unsigned short* xn1  = ws + 12582912;      // [8192][1024]
  unsigned short* Qb   = ws + 20971520;      // [B,H,S,D]
  unsigned short* Kb   = ws + 29360128;      // [B,H,S,D]
  unsigned short* Vtb  = ws + 37748736;      // [B,H,D,S]
  unsigned short* aout = xn1;                // reuse (xn1 dead after QKV gemm)
  unsigned short* hn   = Qb;                 // reuse (Q dead after attention)
  unsigned short* hbuf = Kb;                 // [8192][4096] overlaps K/Vt (dead)

  transpose_w_kernel<<<dim3(48, 16), 256, 0, stream>>>(qkv_w, wqkv, 1024, 3072);
  transpose_w_kernel<<<dim3(16, 16), 256, 0, stream>>>(proj_w, wproj, 1024, 1024);
  transpose_w_kernel<<<dim3(64, 16), 256, 0, stream>>>(fc1_w, wfc1, 1024, 4096);
  transpose_w_kernel<<<dim3(16, 64), 256, 0, stream>>>(fc2_w, wfc2, 4096, 1024);

  ln_kernel<<<ROWS, 256, 0, stream>>>(x, ln1_w, ln1_b, xn1);

  gemm_bt<0><<<dim3(24, 64), 256, 0, stream>>>(xn1, wqkv, qkv_b,
      nullptr, nullptr, nullptr, Qb, Kb, Vtb, ROWS, 3072, 1024);

  attn_kernel<<<dim3(16, 64), 256, 0, stream>>>(Qb, Kb, Vtb, aout);

  gemm_bt<1><<<dim3(8, 64), 256, 0, stream>>>(aout, wproj, proj_b,
      x, out, nullptr, nullptr, nullptr, nullptr, ROWS, 1024, 1024);

  ln_kernel<<<ROWS, 256, 0, stream>>>(out, ln2_w, ln2_b, hn);

  gemm_bt<2><<<dim3(32, 64), 256, 0, stream>>>(hn, wfc1, fc1_b,
      nullptr, nullptr, hbuf, nullptr, nullptr, nullptr, ROWS, 4096, 1024);

  gemm_bt<3><<<dim3(8, 64), 256, 0, stream>>>(hbuf, wfc2, fc2_b,
      out, out, nullptr, nullptr, nullptr, nullptr, ROWS, 1024, 4096);
}

// Round 11
// 566.720 us; speedup vs baseline: 1.5305x; 1.0558x over previous
//
#include <hip/hip_runtime.h>

#define DIM 1024
#define SEQ 2048
#define BATCH 4
#define NH 16
#define HD 64
#define MLP 4096
#define ROWS (BATCH*SEQ)

typedef __bf16 bf16x8 __attribute__((ext_vector_type(8)));
typedef float f32x4 __attribute__((ext_vector_type(4)));
typedef __attribute__((address_space(3))) void as3void;
typedef const __attribute__((address_space(1))) void as1void;

__device__ __forceinline__ unsigned short f2bf(float f) {
  unsigned u = __builtin_bit_cast(unsigned, f);
  u = (u + 0x7FFFu + ((u >> 16) & 1u)) >> 16;
  return (unsigned short)u;
}

__device__ __forceinline__ void gload_lds16(const void* gp, const void* lp) {
  __builtin_amdgcn_global_load_lds(
      (as1void*)(unsigned long long)(size_t)gp,
      (as3void*)(unsigned int)(size_t)lp,
      16, 0, 0);
}

// ---------------- weight transpose fp32[K][N] -> bf16[N][K] ----------------
__global__ __launch_bounds__(256) void transpose_w_kernel(
    const float* __restrict__ in, unsigned short* __restrict__ out, int K, int N)
{
  __shared__ float tile[64][65];
  const int k0 = blockIdx.y * 64, n0 = blockIdx.x * 64;
  const int tc = threadIdx.x & 63, tr = threadIdx.x >> 6;
#pragma unroll
  for (int i = 0; i < 64; i += 4)
    tile[tr + i][tc] = in[(size_t)(k0 + tr + i) * N + n0 + tc];
  __syncthreads();
#pragma unroll
  for (int i = 0; i < 64; i += 4)
    out[(size_t)(n0 + tr + i) * K + k0 + tc] = f2bf(tile[tc][tr + i]);
}

// ---------------- layernorm fp32 -> bf16 ----------------
__global__ __launch_bounds__(256) void ln_kernel(
    const float* __restrict__ x, const float* __restrict__ w, const float* __restrict__ b,
    unsigned short* __restrict__ out)
{
  const int row = blockIdx.x;
  const int t = threadIdx.x;
  const int lane = t & 63, wave = t >> 6;
  const float* xr = x + (size_t)row * DIM;
  float4 v = *(const float4*)&xr[t * 4];
  float s = v.x + v.y + v.z + v.w;
  float s2 = v.x * v.x + v.y * v.y + v.z * v.z + v.w * v.w;
#pragma unroll
  for (int o = 1; o < 64; o <<= 1) {
    s += __shfl_xor(s, o);
    s2 += __shfl_xor(s2, o);
  }
  __shared__ float red[8];
  if (lane == 0) { red[wave] = s; red[4 + wave] = s2; }
  __syncthreads();
  s = red[0] + red[1] + red[2] + red[3];
  s2 = red[4] + red[5] + red[6] + red[7];
  const float mu = s * (1.f / DIM);
  const float var = s2 * (1.f / DIM) - mu * mu;
  const float rstd = rsqrtf(var + 1e-5f);
  float4 wv = *(const float4*)&w[t * 4];
  float4 bv = *(const float4*)&b[t * 4];
  ushort4 o;
  o.x = f2bf((v.x - mu) * rstd * wv.x + bv.x);
  o.y = f2bf((v.y - mu) * rstd * wv.y + bv.y);
  o.z = f2bf((v.z - mu) * rstd * wv.z + bv.z);
  o.w = f2bf((v.w - mu) * rstd * wv.w + bv.w);
  *(ushort4*)&out[(size_t)row * DIM + t * 4] = o;
}

// ---------------- GEMM v2: C[M][N] = A[M][K](bf16) x Bt[N][K](bf16) + bias ----------------
// 128x128 tile, BK=64, 4 waves, double-buffered 2-phase (stage t+1 BEFORE compute t,
// ONE barrier per K-tile), XOR-swizzled LDS (128B rows, 8 granules: 2-way = free
// within quarter-wave phases), setprio around MFMA. Epilogue unchanged (verified).
// MODE 0: QKV scatter (Q scaled 0.125)  1: +res -> fp32  2: GELU -> bf16  3: +res -> fp32
template <int MODE>
__global__ __launch_bounds__(256) void gemm_bt(
    const unsigned short* __restrict__ A,
    const unsigned short* __restrict__ Bt,
    const float* __restrict__ bias,
    const float* resf, float* outf, unsigned short* outb,
    unsigned short* Qo, unsigned short* Ko, unsigned short* Vto,
    int M, int N, int K)
{
  __shared__ __align__(16) unsigned short sA[2][128 * 64]; // 32 KB
  __shared__ __align__(16) unsigned short sB[2][128 * 64]; // 32 KB
  const int tid = threadIdx.x;
  const int wave = tid >> 6, lane = tid & 63;

  // bijective XCD swizzle (all grids have nwg % 8 == 0)
  const int nbx = gridDim.x;
  const int nwg = nbx * gridDim.y;
  const int bid = blockIdx.y * nbx + blockIdx.x;
  const int cpx = nwg >> 3;
  const int swz = (bid & 7) * cpx + (bid >> 3);
  const int n0 = (swz % nbx) * 128;
  const int m0 = (swz / nbx) * 128;

  // staging: 4 rounds/operand/K-tile; round j: thread covers phys row j*32+(tid>>3),
  // phys granule tid&7. Pre-swizzled source granule = (tid&7) ^ ((tid>>3)&7).
  const int srow = tid >> 3;                       // 0..31
  const int sgl = (tid & 7) ^ (srow & 7);          // logical (source) granule
  const unsigned short* pA = A + (size_t)(m0 + srow) * K + sgl * 8;
  const unsigned short* pB = Bt + (size_t)(n0 + srow) * K + sgl * 8;

  const int wr = wave >> 1, wc = wave & 1;
  const int fl = lane & 15, fh = lane >> 4;
  f32x4 acc[4][4] = {};

  const int NT = K >> 6;

  // prologue: stage K-tile 0 into buf 0
#pragma unroll
  for (int j = 0; j < 4; ++j) {
    gload_lds16(pA + (size_t)j * 32 * K, &sA[0][j * 2048 + tid * 8]);
    gload_lds16(pB + (size_t)j * 32 * K, &sB[0][j * 2048 + tid * 8]);
  }
  __syncthreads(); // drains vmcnt(0)

  for (int t = 0; t < NT; ++t) {
    const int cur = t & 1;
    if (t + 1 < NT) { // stage next tile FIRST (latency hides under MFMA below)
      const size_t ko = (size_t)(t + 1) * 64;
#pragma unroll
      for (int j = 0; j < 4; ++j) {
        gload_lds16(pA + (size_t)j * 32 * K + ko, &sA[cur ^ 1][j * 2048 + tid * 8]);
        gload_lds16(pB + (size_t)j * 32 * K + ko, &sB[cur ^ 1][j * 2048 + tid * 8]);
      }
    }
#pragma unroll
    for (int ks = 0; ks < 2; ++ks) {
      // logical granule ks*4+fh; phys = logical ^ (row&7), row&7 == fl&7
      const int pg = ((ks * 4 + fh) ^ (fl & 7)) * 8;
      bf16x8 af[4], bfr[4];
#pragma unroll
      for (int f = 0; f < 4; ++f)
        af[f] = *(const bf16x8*)&sA[cur][(wr * 64 + f * 16 + fl) * 64 + pg];
#pragma unroll
      for (int f = 0; f < 4; ++f)
        bfr[f] = *(const bf16x8*)&sB[cur][(wc * 64 + f * 16 + fl) * 64 + pg];
      __builtin_amdgcn_s_setprio(1);
#pragma unroll
      for (int i = 0; i < 4; ++i)
#pragma unroll
        for (int j = 0; j < 4; ++j)
          acc[i][j] = __builtin_amdgcn_mfma_f32_16x16x32_bf16(af[i], bfr[j], acc[i][j], 0, 0, 0);
      __builtin_amdgcn_s_setprio(0);
    }
    __syncthreads(); // one barrier per K-tile: drains staging + protects dbuf swap
  }

#pragma unroll
  for (int i = 0; i < 4; ++i) {
    const int rowb = m0 + wr * 64 + i * 16 + fh * 4;
#pragma unroll
    for (int j = 0; j < 4; ++j) {
      const int col = n0 + wc * 64 + j * 16 + fl;
      const float bv = bias[col];
#pragma unroll
      for (int r = 0; r < 4; ++r) {
        const int row = rowb + r;
        float v = acc[i][j][r] + bv;
        if constexpr (MODE == 0) {
          const int which = col >> 10;
          const int h = (col >> 6) & 15;
          const int d = col & 63;
          const int b = row >> 11, s = row & 2047;
          const size_t bh = (size_t)(b * 16 + h);
          if (which == 0)      Qo[(bh * SEQ + s) * HD + d] = f2bf(v * 0.125f);
          else if (which == 1) Ko[(bh * SEQ + s) * HD + d] = f2bf(v);
          else                 Vto[(bh * HD + d) * SEQ + s] = f2bf(v);
        } else if constexpr (MODE == 2) {
          const float g = 0.5f * v * (1.0f + erff(v * 0.70710678118f));
          outb[(size_t)row * N + col] = f2bf(g);
        } else {
          outf[(size_t)row * N + col] = resf[(size_t)row * N + col] + v;
        }
      }
    }
  }
}

// ---------------- causal flash attention (v4: swapped ops + balanced pairing) ----------------
// grid (16, 64 bh); block bx processes qt=bx THEN qt=31-bx  => exactly 33 K-tiles
// per block (perfect balance; 1024 blocks x 40KB = all-resident at 4 blocks/CU).
// S^T = mfma(K,Q): lane owns one q-row -> softmax = in-reg + 2 shfl.
// K AND V staged in LDS (dbuf, pre-swizzled global source, 0-conflict pattern).
// P bounced via per-wave LDS as 4x 8B packed stores (conflict-light).
__global__ __launch_bounds__(256, 4) void attn_kernel(
    const unsigned short* __restrict__ Q,
    const unsigned short* __restrict__ Kt,
    const unsigned short* __restrict__ Vt,
    unsigned short* __restrict__ Ao)
{
  __shared__ __align__(16) char sK[2][8192];
  __shared__ __align__(16) char sV[2][8192];
  __shared__ __align__(16) char sP[4][2048];

  const int bh = blockIdx.y;
  const int wave = threadIdx.x >> 6, lane = threadIdx.x & 63;
  const int fl = lane & 15, fh = lane >> 4;
  const char* Kb = (const char*)(Kt + (size_t)bh * SEQ * HD);
  const char* Vb = (const char*)(Vt + (size_t)bh * HD * SEQ);
  const unsigned short* Qb = Q + (size_t)bh * SEQ * HD;
  char* pbase = sP[wave];
  const int pswz = (fl & 7) << 4;
  const int b = bh >> 4, h = bh & 15;

  // staging geometry: 8KB tile = 8 chunks of 1KB; wave stages chunks {wave, wave+4}
  const int sg_row_in = lane >> 3;                          // row & 7 within chunk
  const int sg_colb = ((lane & 7) * 16) ^ (sg_row_in << 4); // pre-swizzled src col

  for (int phase = 0; phase < 2; ++phase) {
    const int qt = (phase == 0) ? (int)blockIdx.x : 31 - (int)blockIdx.x;
    const int qw = qt * 64 + wave * 16;
    const int nkt = qt + 1;                 // uniform across waves

    // Q fragment (B-operand of swapped QK): lane fl holds Q[qw+fl][kk*32+fh*8..+8]
    bf16x8 bq[2];
#pragma unroll
    for (int kk = 0; kk < 2; ++kk)
      bq[kk] = *(const bf16x8*)&Qb[(size_t)(qw + fl) * HD + kk * 32 + fh * 8];

    f32x4 accO[4] = {};                     // O[q=qw+fl][d = dc*16 + fh*4 + r]
    float mr = -1e30f, lr = 0.f;

    // prologue: stage K/V tile 0 into buf 0
#pragma unroll
    for (int i = 0; i < 2; ++i) {
      const int chunk = i * 4 + wave;
      const int row = chunk * 8 + sg_row_in;
      gload_lds16(Kb + (size_t)row * 128 + sg_colb, sK[0] + chunk * 1024);
      gload_lds16(Vb + (size_t)row * (SEQ * 2) + sg_colb, sV[0] + chunk * 1024);
    }
    __syncthreads();

    for (int t = 0; t < nkt; ++t) {
      const int kbase = t * 64;
      const int cur = t & 1;
      if (t + 1 < nkt) { // prefetch next K/V tile into other buffer
        const int kb2 = kbase + 64;
#pragma unroll
        for (int i = 0; i < 2; ++i) {
          const int chunk = i * 4 + wave;
          const int row = chunk * 8 + sg_row_in;
          gload_lds16(Kb + (size_t)(kb2 + row) * 128 + sg_colb, sK[cur ^ 1] + chunk * 1024);
          gload_lds16(Vb + (size_t)row * (SEQ * 2) + kb2 * 2 + sg_colb, sV[cur ^ 1] + chunk * 1024);
        }
      }

      // ---- S^T = K * Q^T : accT[fc][r] = S[q=qw+fl][k=kbase+fc*16+fh*4+r] ----
      f32x4 accT[4] = {};
      __builtin_amdgcn_s_setprio(1);
#pragma unroll
      for (int kk = 0; kk < 2; ++kk) {
        const int cb = (kk * 64 + fh * 16) ^ pswz;
#pragma unroll
        for (int fc = 0; fc < 4; ++fc) {
          const bf16x8 ak = *(const bf16x8*)(sK[cur] + (fc * 16 + fl) * 128 + cb);
          accT[fc] = __builtin_amdgcn_mfma_f32_16x16x32_bf16(ak, bq[kk], accT[fc], 0, 0, 0);
        }
      }
      __builtin_amdgcn_s_setprio(0);

      if (t == nkt - 1) { // causal mask (diagonal tile only)
        const int rowq = qw + fl;
#pragma unroll
        for (int fc = 0; fc < 4; ++fc)
#pragma unroll
          for (int r = 0; r < 4; ++r) {
            const int colk = kbase + fc * 16 + fh * 4 + r;
            if (colk > rowq) accT[fc][r] = -1e30f;
          }
      }

      // ---- online softmax: lane owns one q-row (15 in-reg max + 2 shfl) ----
      float mx = fmaxf(fmaxf(fmaxf(accT[0][0], accT[0][1]), fmaxf(accT[0][2], accT[0][3])),
                       fmaxf(fmaxf(accT[1][0], accT[1][1]), fmaxf(accT[1][2], accT[1][3])));
      mx = fmaxf(mx, fmaxf(fmaxf(fmaxf(accT[2][0], accT[2][1]), fmaxf(accT[2][2], accT[2][3])),
                           fmaxf(fmaxf(accT[3][0], accT[3][1]), fmaxf(accT[3][2], accT[3][3]))));
      mx = fmaxf(mx, __shfl_xor(mx, 16));
      mx = fmaxf(mx, __shfl_xor(mx, 32));
      const float mnew = fmaxf(mr, mx);
      const float alpha = __expf(mr - mnew);
      mr = mnew;
      float rs = 0.f;
#pragma unroll
      for (int fc = 0; fc < 4; ++fc)
#pragma unroll
        for (int r = 0; r < 4; ++r) {
          const float p = __expf(accT[fc][r] - mnew);
          accT[fc][r] = p;
          rs += p;
        }
      rs += __shfl_xor(rs, 16);
      rs += __shfl_xor(rs, 32);
      lr = lr * alpha + rs;
#pragma unroll
      for (int dc = 0; dc < 4; ++dc)
        accO[dc] *= alpha;

      // ---- P -> LDS: pack r-quad to 8B, one store per fc (same byte image) ----
#pragma unroll
      for (int fc = 0; fc < 4; ++fc) {
        uint2 pk;
        pk.x = (unsigned)f2bf(accT[fc][0]) | ((unsigned)f2bf(accT[fc][1]) << 16);
        pk.y = (unsigned)f2bf(accT[fc][2]) | ((unsigned)f2bf(accT[fc][3]) << 16);
        *(uint2*)(pbase + fl * 128 + ((fc * 32 + fh * 8) ^ pswz)) = pk;
      }

      // ---- O^T += V^T * P^T (V from LDS, 0-conflict swizzled reads) ----
      __builtin_amdgcn_s_setprio(1);
#pragma unroll
      for (int kk = 0; kk < 2; ++kk) {
        const int cb = (kk * 64 + fh * 16) ^ pswz;
        const bf16x8 pb = *(const bf16x8*)(pbase + fl * 128 + cb);
#pragma unroll
        for (int dc = 0; dc < 4; ++dc) {
          const bf16x8 av = *(const bf16x8*)(sV[cur] + (dc * 16 + fl) * 128 + cb);
          accO[dc] = __builtin_amdgcn_mfma_f32_16x16x32_bf16(av, pb, accO[dc], 0, 0, 0);
        }
      }
      __builtin_amdgcn_s_setprio(0);

      __syncthreads(); // protects dbuf swap (drains prefetch)
    }

    // epilogue: lane owns q-row qw+fl; d = dc*16 + fh*4 + r
    const float inv = 1.0f / lr;
    unsigned short* orow = Ao + ((size_t)b * SEQ + qw + fl) * DIM + h * HD;
#pragma unroll
    for (int dc = 0; dc < 4; ++dc) {
      ushort4 o;
      o.x = f2bf(accO[dc][0] * inv);
      o.y = f2bf(accO[dc][1] * inv);
      o.z = f2bf(accO[dc][2] * inv);
      o.w = f2bf(accO[dc][3] * inv);
      *(ushort4*)&orow[dc * 16 + fh * 4] = o;
    }
  }
}

// ---------------- launcher ----------------
extern "C" void kernel_launch(void* const* d_in, const int* in_sizes, int n_in,
                              void* d_out, int out_size, void* d_ws, size_t ws_size,
                              hipStream_t stream)
{
  const float* x      = (const float*)d_in[0];
  const float* ln1_w  = (const float*)d_in[1];
  const float* ln1_b  = (const float*)d_in[2];
  const float* qkv_w  = (const float*)d_in[3];
  const float* qkv_b  = (const float*)d_in[4];
  const float* proj_w = (const float*)d_in[5];
  const float* proj_b = (const float*)d_in[6];
  const float* ln2_w  = (const float*)d_in[7];
  const float* ln2_b  = (const float*)d_in[8];
  const float* fc1_w  = (const float*)d_in[9];
  const float* fc1_b  = (const float*)d_in[10];
  const float* fc2_w  = (const float*)d_in[11];
  const float* fc2_b  = (const float*)d_in[12];
  float* out = (float*)d_out;
  unsigned short* ws = (unsigned short*)d_ws;

  // ws layout (bf16 element offsets); total = 125,829,120 bytes
  unsigned short* wqkv = ws;                 // [3072][1024]
  unsigned short* wproj = ws + 3145728;      // [1024][1024]
  unsigned short* wfc1 = ws + 4194304;       // [4096][1024]
  unsigned short* wfc2 = ws + 8388608;       // [1024][4096]
  unsigned short* xn1  = ws + 12582912;      // [8192][1024]
  unsigned short* Qb   = ws + 20971520;      // [B,H,S,D]
  unsigned short* Kb   = ws + 29360128;      // [B,H,S,D]
  unsigned short* Vtb  = ws + 37748736;      // [B,H,D,S]
  unsigned short* aout = xn1;                // reuse (xn1 dead after QKV gemm)
  unsigned short* hn   = Qb;                 // reuse (Q dead after attention)
  unsigned short* hbuf = Kb;                 // [8192][4096] overlaps K/Vt (dead)

  transpose_w_kernel<<<dim3(48, 16), 256, 0, stream>>>(qkv_w, wqkv, 1024, 3072);
  transpose_w_kernel<<<dim3(16, 16), 256, 0, stream>>>(proj_w, wproj, 1024, 1024);
  transpose_w_kernel<<<dim3(64, 16), 256, 0, stream>>>(fc1_w, wfc1, 1024, 4096);
  transpose_w_kernel<<<dim3(16, 64), 256, 0, stream>>>(fc2_w, wfc2, 4096, 1024);

  ln_kernel<<<ROWS, 256, 0, stream>>>(x, ln1_w, ln1_b, xn1);

  gemm_bt<0><<<dim3(24, 64), 256, 0, stream>>>(xn1, wqkv, qkv_b,
      nullptr, nullptr, nullptr, Qb, Kb, Vtb, ROWS, 3072, 1024);

  attn_kernel<<<dim3(16, 64), 256, 0, stream>>>(Qb, Kb, Vtb, aout);

  gemm_bt<1><<<dim3(8, 64), 256, 0, stream>>>(aout, wproj, proj_b,
      x, out, nullptr, nullptr, nullptr, nullptr, ROWS, 1024, 1024);

  ln_kernel<<<ROWS, 256, 0, stream>>>(out, ln2_w, ln2_b, hn);

  gemm_bt<2><<<dim3(32, 64), 256, 0, stream>>>(hn, wfc1, fc1_b,
      nullptr, nullptr, hbuf, nullptr, nullptr, nullptr, ROWS, 4096, 1024);

  gemm_bt<3><<<dim3(8, 64), 256, 0, stream>>>(hbuf, wfc2, fc2_b,
      out, out, nullptr, nullptr, nullptr, nullptr, ROWS, 1024, 4096);
}

// Round 12
// 563.428 us; speedup vs baseline: 1.5395x; 1.0058x over previous
//
#include <hip/hip_runtime.h>

#define DIM 1024
#define SEQ 2048
#define BATCH 4
#define NH 16
#define HD 64
#define MLP 4096
#define ROWS (BATCH*SEQ)

typedef __bf16 bf16x8 __attribute__((ext_vector_type(8)));
typedef float f32x4 __attribute__((ext_vector_type(4)));
typedef __attribute__((address_space(3))) void as3void;
typedef const __attribute__((address_space(1))) void as1void;

__device__ __forceinline__ unsigned short f2bf(float f) {
  unsigned u = __builtin_bit_cast(unsigned, f);
  u = (u + 0x7FFFu + ((u >> 16) & 1u)) >> 16;
  return (unsigned short)u;
}

__device__ __forceinline__ void gload_lds16(const void* gp, const void* lp) {
  __builtin_amdgcn_global_load_lds(
      (as1void*)(unsigned long long)(size_t)gp,
      (as3void*)(unsigned int)(size_t)lp,
      16, 0, 0);
}

// ---------------- weight transpose fp32[K][N] -> bf16[N][K] ----------------
__global__ __launch_bounds__(256) void transpose_w_kernel(
    const float* __restrict__ in, unsigned short* __restrict__ out, int K, int N)
{
  __shared__ float tile[64][65];
  const int k0 = blockIdx.y * 64, n0 = blockIdx.x * 64;
  const int tc = threadIdx.x & 63, tr = threadIdx.x >> 6;
#pragma unroll
  for (int i = 0; i < 64; i += 4)
    tile[tr + i][tc] = in[(size_t)(k0 + tr + i) * N + n0 + tc];
  __syncthreads();
#pragma unroll
  for (int i = 0; i < 64; i += 4)
    out[(size_t)(n0 + tr + i) * K + k0 + tc] = f2bf(tile[tc][tr + i]);
}

// ---------------- layernorm fp32 -> bf16 ----------------
__global__ __launch_bounds__(256) void ln_kernel(
    const float* __restrict__ x, const float* __restrict__ w, const float* __restrict__ b,
    unsigned short* __restrict__ out)
{
  const int row = blockIdx.x;
  const int t = threadIdx.x;
  const int lane = t & 63, wave = t >> 6;
  const float* xr = x + (size_t)row * DIM;
  float4 v = *(const float4*)&xr[t * 4];
  float s = v.x + v.y + v.z + v.w;
  float s2 = v.x * v.x + v.y * v.y + v.z * v.z + v.w * v.w;
#pragma unroll
  for (int o = 1; o < 64; o <<= 1) {
    s += __shfl_xor(s, o);
    s2 += __shfl_xor(s2, o);
  }
  __shared__ float red[8];
  if (lane == 0) { red[wave] = s; red[4 + wave] = s2; }
  __syncthreads();
  s = red[0] + red[1] + red[2] + red[3];
  s2 = red[4] + red[5] + red[6] + red[7];
  const float mu = s * (1.f / DIM);
  const float var = s2 * (1.f / DIM) - mu * mu;
  const float rstd = rsqrtf(var + 1e-5f);
  float4 wv = *(const float4*)&w[t * 4];
  float4 bv = *(const float4*)&b[t * 4];
  ushort4 o;
  o.x = f2bf((v.x - mu) * rstd * wv.x + bv.x);
  o.y = f2bf((v.y - mu) * rstd * wv.y + bv.y);
  o.z = f2bf((v.z - mu) * rstd * wv.z + bv.z);
  o.w = f2bf((v.w - mu) * rstd * wv.w + bv.w);
  *(ushort4*)&out[(size_t)row * DIM + t * 4] = o;
}

// ---------------- GEMM v3: C[M][N] = A[M][K](bf16) x Bt[N][K](bf16) + bias ----------------
// 128x128 tile, BK=64, 4 waves, double-buffered with T4 COUNTED VMCNT:
// raw s_barrier + s_waitcnt vmcnt(8) -- prefetch loads stay in flight across
// barriers (never drained to 0 in steady state). XOR-swizzled LDS (conflict-free,
// verified R11: BANK_CONFLICT=0), setprio around MFMA. Epilogue unchanged.
// MODE 0: QKV scatter (Q scaled 0.125)  1: +res -> fp32  2: GELU -> bf16  3: +res -> fp32
template <int MODE>
__global__ __launch_bounds__(256) void gemm_bt(
    const unsigned short* __restrict__ A,
    const unsigned short* __restrict__ Bt,
    const float* __restrict__ bias,
    const float* resf, float* outf, unsigned short* outb,
    unsigned short* Qo, unsigned short* Ko, unsigned short* Vto,
    int M, int N, int K)
{
  __shared__ __align__(16) unsigned short sA[2][128 * 64]; // 32 KB
  __shared__ __align__(16) unsigned short sB[2][128 * 64]; // 32 KB
  const int tid = threadIdx.x;
  const int wave = tid >> 6, lane = tid & 63;

  // bijective XCD swizzle (all grids have nwg % 8 == 0)
  const int nbx = gridDim.x;
  const int nwg = nbx * gridDim.y;
  const int bid = blockIdx.y * nbx + blockIdx.x;
  const int cpx = nwg >> 3;
  const int swz = (bid & 7) * cpx + (bid >> 3);
  const int n0 = (swz % nbx) * 128;
  const int m0 = (swz / nbx) * 128;

  // staging: 4 rounds/operand/K-tile; round j: thread covers phys row j*32+(tid>>3),
  // phys granule tid&7. Pre-swizzled source granule = (tid&7) ^ ((tid>>3)&7).
  const int srow = tid >> 3;                       // 0..31
  const int sgl = (tid & 7) ^ (srow & 7);          // logical (source) granule
  const unsigned short* pA = A + (size_t)(m0 + srow) * K + sgl * 8;
  const unsigned short* pB = Bt + (size_t)(n0 + srow) * K + sgl * 8;

  const int wr = wave >> 1, wc = wave & 1;
  const int fl = lane & 15, fh = lane >> 4;
  f32x4 acc[4][4] = {};

  const int NT = K >> 6;

  // prologue: issue tile-0 staging (8 loads/wave in flight)
#pragma unroll
  for (int j = 0; j < 4; ++j) {
    gload_lds16(pA + (size_t)j * 32 * K, &sA[0][j * 2048 + tid * 8]);
    gload_lds16(pB + (size_t)j * 32 * K, &sB[0][j * 2048 + tid * 8]);
  }

  for (int t = 0; t < NT; ++t) {
    const int cur = t & 1;
    if (t + 1 < NT) {
      // issue next tile's 8 loads, then wait for CURRENT tile only (vmcnt(8):
      // the 8 just-issued loads remain in flight across both barriers)
      const size_t ko = (size_t)(t + 1) * 64;
#pragma unroll
      for (int j = 0; j < 4; ++j) {
        gload_lds16(pA + (size_t)j * 32 * K + ko, &sA[cur ^ 1][j * 2048 + tid * 8]);
        gload_lds16(pB + (size_t)j * 32 * K + ko, &sB[cur ^ 1][j * 2048 + tid * 8]);
      }
      asm volatile("s_waitcnt vmcnt(8)" ::: "memory");
    } else {
      asm volatile("s_waitcnt vmcnt(0)" ::: "memory");
    }
    __builtin_amdgcn_s_barrier(); // tile t fully staged (all waves waited)

#pragma unroll
    for (int ks = 0; ks < 2; ++ks) {
      // logical granule ks*4+fh; phys = logical ^ (row&7), row&7 == fl&7
      const int pg = ((ks * 4 + fh) ^ (fl & 7)) * 8;
      bf16x8 af[4], bfr[4];
#pragma unroll
      for (int f = 0; f < 4; ++f)
        af[f] = *(const bf16x8*)&sA[cur][(wr * 64 + f * 16 + fl) * 64 + pg];
#pragma unroll
      for (int f = 0; f < 4; ++f)
        bfr[f] = *(const bf16x8*)&sB[cur][(wc * 64 + f * 16 + fl) * 64 + pg];
      __builtin_amdgcn_s_setprio(1);
#pragma unroll
      for (int i = 0; i < 4; ++i)
#pragma unroll
        for (int j = 0; j < 4; ++j)
          acc[i][j] = __builtin_amdgcn_mfma_f32_16x16x32_bf16(af[i], bfr[j], acc[i][j], 0, 0, 0);
      __builtin_amdgcn_s_setprio(0);
    }
    __builtin_amdgcn_s_barrier(); // all waves done reading buf[cur] (reused at t+2)
  }

#pragma unroll
  for (int i = 0; i < 4; ++i) {
    const int rowb = m0 + wr * 64 + i * 16 + fh * 4;
#pragma unroll
    for (int j = 0; j < 4; ++j) {
      const int col = n0 + wc * 64 + j * 16 + fl;
      const float bv = bias[col];
#pragma unroll
      for (int r = 0; r < 4; ++r) {
        const int row = rowb + r;
        float v = acc[i][j][r] + bv;
        if constexpr (MODE == 0) {
          const int which = col >> 10;
          const int h = (col >> 6) & 15;
          const int d = col & 63;
          const int b = row >> 11, s = row & 2047;
          const size_t bh = (size_t)(b * 16 + h);
          if (which == 0)      Qo[(bh * SEQ + s) * HD + d] = f2bf(v * 0.125f);
          else if (which == 1) Ko[(bh * SEQ + s) * HD + d] = f2bf(v);
          else                 Vto[(bh * HD + d) * SEQ + s] = f2bf(v);
        } else if constexpr (MODE == 2) {
          const float g = 0.5f * v * (1.0f + erff(v * 0.70710678118f));
          outb[(size_t)row * N + col] = f2bf(g);
        } else {
          outf[(size_t)row * N + col] = resf[(size_t)row * N + col] + v;
        }
      }
    }
  }
}

// ---------------- causal flash attention (v4: swapped ops + balanced pairing) ----------------
// grid (16, 64 bh); block bx processes qt=bx THEN qt=31-bx  => exactly 33 K-tiles
// per block (perfect balance; 1024 blocks x 40KB = all-resident at 4 blocks/CU).
// S^T = mfma(K,Q): lane owns one q-row -> softmax = in-reg + 2 shfl.
// K AND V staged in LDS (dbuf, pre-swizzled global source, 0-conflict pattern).
// P bounced via per-wave LDS as 4x 8B packed stores (conflict-light).
__global__ __launch_bounds__(256, 4) void attn_kernel(
    const unsigned short* __restrict__ Q,
    const unsigned short* __restrict__ Kt,
    const unsigned short* __restrict__ Vt,
    unsigned short* __restrict__ Ao)
{
  __shared__ __align__(16) char sK[2][8192];
  __shared__ __align__(16) char sV[2][8192];
  __shared__ __align__(16) char sP[4][2048];

  const int bh = blockIdx.y;
  const int wave = threadIdx.x >> 6, lane = threadIdx.x & 63;
  const int fl = lane & 15, fh = lane >> 4;
  const char* Kb = (const char*)(Kt + (size_t)bh * SEQ * HD);
  const char* Vb = (const char*)(Vt + (size_t)bh * HD * SEQ);
  const unsigned short* Qb = Q + (size_t)bh * SEQ * HD;
  char* pbase = sP[wave];
  const int pswz = (fl & 7) << 4;
  const int b = bh >> 4, h = bh & 15;

  // staging geometry: 8KB tile = 8 chunks of 1KB; wave stages chunks {wave, wave+4}
  const int sg_row_in = lane >> 3;                          // row & 7 within chunk
  const int sg_colb = ((lane & 7) * 16) ^ (sg_row_in << 4); // pre-swizzled src col

  for (int phase = 0; phase < 2; ++phase) {
    const int qt = (phase == 0) ? (int)blockIdx.x : 31 - (int)blockIdx.x;
    const int qw = qt * 64 + wave * 16;
    const int nkt = qt + 1;                 // uniform across waves

    // Q fragment (B-operand of swapped QK): lane fl holds Q[qw+fl][kk*32+fh*8..+8]
    bf16x8 bq[2];
#pragma unroll
    for (int kk = 0; kk < 2; ++kk)
      bq[kk] = *(const bf16x8*)&Qb[(size_t)(qw + fl) * HD + kk * 32 + fh * 8];

    f32x4 accO[4] = {};                     // O[q=qw+fl][d = dc*16 + fh*4 + r]
    float mr = -1e30f, lr = 0.f;

    // prologue: stage K/V tile 0 into buf 0
#pragma unroll
    for (int i = 0; i < 2; ++i) {
      const int chunk = i * 4 + wave;
      const int row = chunk * 8 + sg_row_in;
      gload_lds16(Kb + (size_t)row * 128 + sg_colb, sK[0] + chunk * 1024);
      gload_lds16(Vb + (size_t)row * (SEQ * 2) + sg_colb, sV[0] + chunk * 1024);
    }
    __syncthreads();

    for (int t = 0; t < nkt; ++t) {
      const int kbase = t * 64;
      const int cur = t & 1;
      if (t + 1 < nkt) { // prefetch next K/V tile into other buffer
        const int kb2 = kbase + 64;
#pragma unroll
        for (int i = 0; i < 2; ++i) {
          const int chunk = i * 4 + wave;
          const int row = chunk * 8 + sg_row_in;
          gload_lds16(Kb + (size_t)(kb2 + row) * 128 + sg_colb, sK[cur ^ 1] + chunk * 1024);
          gload_lds16(Vb + (size_t)row * (SEQ * 2) + kb2 * 2 + sg_colb, sV[cur ^ 1] + chunk * 1024);
        }
      }

      // ---- S^T = K * Q^T : accT[fc][r] = S[q=qw+fl][k=kbase+fc*16+fh*4+r] ----
      f32x4 accT[4] = {};
      __builtin_amdgcn_s_setprio(1);
#pragma unroll
      for (int kk = 0; kk < 2; ++kk) {
        const int cb = (kk * 64 + fh * 16) ^ pswz;
#pragma unroll
        for (int fc = 0; fc < 4; ++fc) {
          const bf16x8 ak = *(const bf16x8*)(sK[cur] + (fc * 16 + fl) * 128 + cb);
          accT[fc] = __builtin_amdgcn_mfma_f32_16x16x32_bf16(ak, bq[kk], accT[fc], 0, 0, 0);
        }
      }
      __builtin_amdgcn_s_setprio(0);

      if (t == nkt - 1) { // causal mask (diagonal tile only)
        const int rowq = qw + fl;
#pragma unroll
        for (int fc = 0; fc < 4; ++fc)
#pragma unroll
          for (int r = 0; r < 4; ++r) {
            const int colk = kbase + fc * 16 + fh * 4 + r;
            if (colk > rowq) accT[fc][r] = -1e30f;
          }
      }

      // ---- online softmax: lane owns one q-row (15 in-reg max + 2 shfl) ----
      float mx = fmaxf(fmaxf(fmaxf(accT[0][0], accT[0][1]), fmaxf(accT[0][2], accT[0][3])),
                       fmaxf(fmaxf(accT[1][0], accT[1][1]), fmaxf(accT[1][2], accT[1][3])));
      mx = fmaxf(mx, fmaxf(fmaxf(fmaxf(accT[2][0], accT[2][1]), fmaxf(accT[2][2], accT[2][3])),
                           fmaxf(fmaxf(accT[3][0], accT[3][1]), fmaxf(accT[3][2], accT[3][3]))));
      mx = fmaxf(mx, __shfl_xor(mx, 16));
      mx = fmaxf(mx, __shfl_xor(mx, 32));
      const float mnew = fmaxf(mr, mx);
      const float alpha = __expf(mr - mnew);
      mr = mnew;
      float rs = 0.f;
#pragma unroll
      for (int fc = 0; fc < 4; ++fc)
#pragma unroll
        for (int r = 0; r < 4; ++r) {
          const float p = __expf(accT[fc][r] - mnew);
          accT[fc][r] = p;
          rs += p;
        }
      rs += __shfl_xor(rs, 16);
      rs += __shfl_xor(rs, 32);
      lr = lr * alpha + rs;
#pragma unroll
      for (int dc = 0; dc < 4; ++dc)
        accO[dc] *= alpha;

      // ---- P -> LDS: pack r-quad to 8B, one store per fc (same byte image) ----
#pragma unroll
      for (int fc = 0; fc < 4; ++fc) {
        uint2 pk;
        pk.x = (unsigned)f2bf(accT[fc][0]) | ((unsigned)f2bf(accT[fc][1]) << 16);
        pk.y = (unsigned)f2bf(accT[fc][2]) | ((unsigned)f2bf(accT[fc][3]) << 16);
        *(uint2*)(pbase + fl * 128 + ((fc * 32 + fh * 8) ^ pswz)) = pk;
      }

      // ---- O^T += V^T * P^T (V from LDS, 0-conflict swizzled reads) ----
      __builtin_amdgcn_s_setprio(1);
#pragma unroll
      for (int kk = 0; kk < 2; ++kk) {
        const int cb = (kk * 64 + fh * 16) ^ pswz;
        const bf16x8 pb = *(const bf16x8*)(pbase + fl * 128 + cb);
#pragma unroll
        for (int dc = 0; dc < 4; ++dc) {
          const bf16x8 av = *(const bf16x8*)(sV[cur] + (dc * 16 + fl) * 128 + cb);
          accO[dc] = __builtin_amdgcn_mfma_f32_16x16x32_bf16(av, pb, accO[dc], 0, 0, 0);
        }
      }
      __builtin_amdgcn_s_setprio(0);

      __syncthreads(); // protects dbuf swap (drains prefetch)
    }

    // epilogue: lane owns q-row qw+fl; d = dc*16 + fh*4 + r
    const float inv = 1.0f / lr;
    unsigned short* orow = Ao + ((size_t)b * SEQ + qw + fl) * DIM + h * HD;
#pragma unroll
    for (int dc = 0; dc < 4; ++dc) {
      ushort4 o;
      o.x = f2bf(accO[dc][0] * inv);
      o.y = f2bf(accO[dc][1] * inv);
      o.z = f2bf(accO[dc][2] * inv);
      o.w = f2bf(accO[dc][3] * inv);
      *(ushort4*)&orow[dc * 16 + fh * 4] = o;
    }
  }
}

// ---------------- launcher ----------------
extern "C" void kernel_launch(void* const* d_in, const int* in_sizes, int n_in,
                              void* d_out, int out_size, void* d_ws, size_t ws_size,
                              hipStream_t stream)
{
  const float* x      = (const float*)d_in[0];
  const float* ln1_w  = (const float*)d_in[1];
  const float* ln1_b  = (const float*)d_in[2];
  const float* qkv_w  = (const float*)d_in[3];
  const float* qkv_b  = (const float*)d_in[4];
  const float* proj_w = (const float*)d_in[5];
  const float* proj_b = (const float*)d_in[6];
  const float* ln2_w  = (const float*)d_in[7];
  const float* ln2_b  = (const float*)d_in[8];
  const float* fc1_w  = (const float*)d_in[9];
  const float* fc1_b  = (const float*)d_in[10];
  const float* fc2_w  = (const float*)d_in[11];
  const float* fc2_b  = (const float*)d_in[12];
  float* out = (float*)d_out;
  unsigned short* ws = (unsigned short*)d_ws;

  // ws layout (bf16 element offsets); total = 125,829,120 bytes
  unsigned short* wqkv = ws;                 // [3072][1024]
  unsigned short* wproj = ws + 3145728;      // [1024][1024]
  unsigned short* wfc1 = ws + 4194304;       // [4096][1024]
  unsigned short* wfc2 = ws + 8388608;       // [1024][4096]
  unsigned short* xn1  = ws + 12582912;      // [8192][1024]
  unsigned short* Qb   = ws + 20971520;      // [B,H,S,D]
  unsigned short* Kb   = ws + 29360128;      // [B,H,S,D]
  unsigned short* Vtb  = ws + 37748736;      // [B,H,D,S]
  unsigned short* aout = xn1;                // reuse (xn1 dead after QKV gemm)
  unsigned short* hn   = Qb;                 // reuse (Q dead after attention)
  unsigned short* hbuf = Kb;                 // [8192][4096] overlaps K/Vt (dead)

  transpose_w_kernel<<<dim3(48, 16), 256, 0, stream>>>(qkv_w, wqkv, 1024, 3072);
  transpose_w_kernel<<<dim3(16, 16), 256, 0, stream>>>(proj_w, wproj, 1024, 1024);
  transpose_w_kernel<<<dim3(64, 16), 256, 0, stream>>>(fc1_w, wfc1, 1024, 4096);
  transpose_w_kernel<<<dim3(16, 64), 256, 0, stream>>>(fc2_w, wfc2, 4096, 1024);

  ln_kernel<<<ROWS, 256, 0, stream>>>(x, ln1_w, ln1_b, xn1);

  gemm_bt<0><<<dim3(24, 64), 256, 0, stream>>>(xn1, wqkv, qkv_b,
      nullptr, nullptr, nullptr, Qb, Kb, Vtb, ROWS, 3072, 1024);

  attn_kernel<<<dim3(16, 64), 256, 0, stream>>>(Qb, Kb, Vtb, aout);

  gemm_bt<1><<<dim3(8, 64), 256, 0, stream>>>(aout, wproj, proj_b,
      x, out, nullptr, nullptr, nullptr, nullptr, ROWS, 1024, 1024);

  ln_kernel<<<ROWS, 256, 0, stream>>>(out, ln2_w, ln2_b, hn);

  gemm_bt<2><<<dim3(32, 64), 256, 0, stream>>>(hn, wfc1, fc1_b,
      nullptr, nullptr, hbuf, nullptr, nullptr, nullptr, ROWS, 4096, 1024);

  gemm_bt<3><<<dim3(8, 64), 256, 0, stream>>>(hbuf, wfc2, fc2_b,
      out, out, nullptr, nullptr, nullptr, nullptr, ROWS, 1024, 4096);
}